// Round 23
// baseline (91.485 us; speedup 1.0000x reference)
//
#include <hip/hip_runtime.h>

// MultiScaleRetention on MI355X (gfx950) — chunked-state formulation v2,
// qkv upgraded to 256x256 tiles (4x less L2 traffic, 2x arith intensity).
// B=2, L=2048, D=1024, H=16, hd=64. fp32 in/out, bf16 MFMA internally.
//
// ws layout (ushort elems), 42 MB:
//   qf[0..4M) | kf[4M..8M) | vf[8M..12M) | ret/xb[12M..16M) |
//   wqb[16M..17M) wkb[17M..18M) wvb[18M..19M) spare | wob[20M..21M)
//   states (4M ushorts = 8MB) ALIASES [16M..20M) (weights dead after qkv)

typedef __attribute__((ext_vector_type(8))) short bf16x8;
typedef __attribute__((ext_vector_type(4))) float f32x4;
typedef __attribute__((ext_vector_type(16))) float f32x16;
typedef __attribute__((ext_vector_type(4))) unsigned short u16x4;
typedef __attribute__((ext_vector_type(8))) unsigned short u16x8;
typedef __attribute__((ext_vector_type(4))) unsigned int u32x4;

__device__ inline unsigned short f2bf(float f) {
    unsigned int u;
    __builtin_memcpy(&u, &f, 4);
    u += 0x7fffu + ((u >> 16) & 1u);
    return (unsigned short)(u >> 16);
}
__device__ inline float bf2f(unsigned short us) {
    unsigned int u = (unsigned int)us << 16;
    float f;
    __builtin_memcpy(&f, &u, 4);
    return f;
}

__device__ inline f32x4 mfma16(bf16x8 a, bf16x8 b, f32x4 c) {
    return __builtin_amdgcn_mfma_f32_16x16x32_bf16(a, b, c, 0, 0, 0);
}
__device__ inline f32x16 mfma32(bf16x8 a, bf16x8 b, f32x16 c) {
    return __builtin_amdgcn_mfma_f32_32x32x16_bf16(a, b, c, 0, 0, 0);
}

__device__ inline void gl16(const unsigned short* g, unsigned short* l) {
    __builtin_amdgcn_global_load_lds(
        (const __attribute__((address_space(1))) unsigned int*)g,
        (__attribute__((address_space(3))) unsigned int*)l,
        16, 0, 0);
}

__device__ inline unsigned cvtpk(float lo, float hi) {
    unsigned r;
    asm("v_cvt_pk_bf16_f32 %0, %1, %2" : "=v"(r) : "v"(lo), "v"(hi));
    return r;
}

// ---------------------------------------------------------------------------
// Kernel 0: f32 -> bf16 conversion of x and the four weight matrices.
// ---------------------------------------------------------------------------
__global__ __launch_bounds__(256) void convert_bf16(
    const float* __restrict__ x,
    const float* __restrict__ wq, const float* __restrict__ wk,
    const float* __restrict__ wv, const float* __restrict__ wo,
    unsigned short* __restrict__ xb,
    unsigned short* __restrict__ wqb, unsigned short* __restrict__ wkb,
    unsigned short* __restrict__ wvb, unsigned short* __restrict__ wob)
{
    int cid = blockIdx.x * 256 + threadIdx.x;
    #pragma unroll
    for (int it = 0; it < 4; ++it, cid += 262144) {
        const float* src;
        unsigned short* dst;
        size_t off;
        if (cid < 524288) {
            src = x; dst = xb; off = (size_t)cid * 8;
        } else {
            const int t = cid - 524288;
            const int seg = t >> 17;
            off = (size_t)(t & 131071) * 8;
            src = seg == 0 ? wq : seg == 1 ? wk : seg == 2 ? wv : wo;
            dst = seg == 0 ? wqb : seg == 1 ? wkb : seg == 2 ? wvb : wob;
        }
        f32x4 a = *(const f32x4*)(src + off);
        f32x4 b = *(const f32x4*)(src + off + 4);
        u32x4 v = { cvtpk(a[0], a[1]), cvtpk(a[2], a[3]),
                    cvtpk(b[0], b[1]), cvtpk(b[2], b[3]) };
        *(u32x4*)(dst + off) = v;
    }
}

// ---------------------------------------------------------------------------
// Kernel 1: QKV projections, 256x256 tile, 512 threads / 8 waves.
// Wave = 128(left/features) x 64(right) output = 8x4 frags. Single 64KB LDS
// buffer, 2-phase: vmcnt(0)+bar -> kt0 frags -> kt0 MFMA while kt1 frags
// load -> lgkm(0)+bar -> stage(next) -> kt1 MFMA. Per-block L2 traffic 1MB
// (vs 4x0.5MB for the 4 equivalent 128^2 blocks).
// ---------------------------------------------------------------------------
__global__ __launch_bounds__(512) void qkv_bf16(
    const unsigned short* __restrict__ xb,
    const unsigned short* __restrict__ wqb, const unsigned short* __restrict__ wkb,
    const unsigned short* __restrict__ wvb,
    unsigned short* __restrict__ qfr, unsigned short* __restrict__ kfr,
    unsigned short* __restrict__ vfr)
{
    __shared__ unsigned short sR[256 * 64];   // right operand tile (32 KB)
    __shared__ unsigned short sL[256 * 64];   // left operand tile  (32 KB)

    const int z = blockIdx.z;
    const int gx = blockIdx.x;                // token tiles (16)
    const int gy = blockIdx.y;                // feature tiles (4)
    const unsigned short* W = (z == 0) ? wqb : (z == 1) ? wkb : wvb;
    const unsigned short* Rs = (z < 2) ? xb : W;
    const unsigned short* Ls = (z < 2) ? W : xb;
    const int rblk = (z < 2) ? gx : gy;       // right matrix tile index
    const int lblk = (z < 2) ? gy : gx;       // left matrix tile index

    const int tid = threadIdx.x;
    const int l = tid & 63, w = tid >> 6;     // 8 waves
    const int lrow = l & 15, koff4 = (l >> 4) * 4;
    const int swz = lrow & 7;
    const int wm = w >> 2, wn = w & 3;        // wave grid 2(left) x 4(right)
    const int lbase = wm * 128;               // left-local base (features)
    const int rbase = wn * 64;                // right-local base

    f32x4 acc[8][4] = {};

    // staging: wave w covers rows [32w, 32w+32) of BOTH tiles
    const int srow = w * 32 + (l >> 3);
    const int scol = ((l & 7) ^ ((l >> 3) & 7)) * 8;
    const unsigned short* gR = Rs + (size_t)(rblk * 256 + srow) * 1024 + scol;
    const unsigned short* gL = Ls + (size_t)(lblk * 256 + srow) * 1024 + scol;
    unsigned short* lRb = sR + (w * 32) * 64;
    unsigned short* lLb = sL + (w * 32) * 64;

    auto stage = [&](int kk) {
        #pragma unroll
        for (int p = 0; p < 4; ++p) {
            gl16(gR + (size_t)p * 8 * 1024 + kk, lRb + p * 512);
            gl16(gL + (size_t)p * 8 * 1024 + kk, lLb + p * 512);
        }
    };

    stage(0);
    for (int kk = 0; kk < 1024; kk += 64) {
        asm volatile("s_waitcnt vmcnt(0)" ::: "memory");     // tile landed
        __builtin_amdgcn_sched_barrier(0);
        __builtin_amdgcn_s_barrier();
        __builtin_amdgcn_sched_barrier(0);

        // kt0 fragments
        bf16x8 a0[8], b0[4];
        {
            const int co = ((l >> 4) ^ swz) * 8;
            #pragma unroll
            for (int f = 0; f < 8; ++f)
                a0[f] = *(const bf16x8*)&sL[(lbase + f * 16 + lrow) * 64 + co];
            #pragma unroll
            for (int f = 0; f < 4; ++f)
                b0[f] = *(const bf16x8*)&sR[(rbase + f * 16 + lrow) * 64 + co];
        }
        asm volatile("s_waitcnt lgkmcnt(0)" ::: "memory");
        __builtin_amdgcn_sched_barrier(0);
        // kt0 MFMAs (kt1 reads issue below and overlap)
        __builtin_amdgcn_s_setprio(1);
        #pragma unroll
        for (int af = 0; af < 8; ++af)
            #pragma unroll
            for (int bf = 0; bf < 4; ++bf)
                acc[af][bf] = mfma16(a0[af], b0[bf], acc[af][bf]);
        __builtin_amdgcn_s_setprio(0);

        // kt1 fragments
        bf16x8 a1[8], b1[4];
        {
            const int co = ((4 + (l >> 4)) ^ swz) * 8;
            #pragma unroll
            for (int f = 0; f < 8; ++f)
                a1[f] = *(const bf16x8*)&sL[(lbase + f * 16 + lrow) * 64 + co];
            #pragma unroll
            for (int f = 0; f < 4; ++f)
                b1[f] = *(const bf16x8*)&sR[(rbase + f * 16 + lrow) * 64 + co];
        }
        asm volatile("s_waitcnt lgkmcnt(0)" ::: "memory");
        __builtin_amdgcn_sched_barrier(0);
        __builtin_amdgcn_s_barrier();            // all waves done with buffer
        __builtin_amdgcn_sched_barrier(0);

        if (kk + 64 < 1024) stage(kk + 64);      // flies under kt1 MFMAs

        __builtin_amdgcn_s_setprio(1);
        #pragma unroll
        for (int af = 0; af < 8; ++af)
            #pragma unroll
            for (int bf = 0; bf < 4; ++bf)
                acc[af][bf] = mfma16(a1[af], b1[bf], acc[af][bf]);
        __builtin_amdgcn_s_setprio(0);
    }

    // epilogue: D col (= right local) = lane&15, row (= left local)
    #pragma unroll
    for (int af = 0; af < 8; ++af) {
        #pragma unroll
        for (int bf = 0; bf < 4; ++bf) {
            const int m = rblk * 256 + rbase + bf * 16 + lrow;     // right index
            const int n0 = lblk * 256 + lbase + af * 16 + koff4;   // left index
            f32x4 v = acc[af][bf];
            unsigned p0 = cvtpk(v[0], v[1]), p1 = cvtpk(v[2], v[3]);
            u16x4 val = { (unsigned short)(p0 & 0xffff), (unsigned short)(p0 >> 16),
                          (unsigned short)(p1 & 0xffff), (unsigned short)(p1 >> 16) };
            if (z < 2) {
                const int bq = m >> 11, s = m & 2047;
                const int h2 = n0 >> 6, dd = n0 & 63;
                const size_t addr = (size_t)((bq * 16 + h2) * 64 + (s >> 5)) * 2048
                                  + (size_t)(dd >> 4) * 512 + (size_t)((dd >> 3) & 1) * 256
                                  + (size_t)(s & 31) * 8 + (dd & 7);
                unsigned short* dst = z ? kfr : qfr;
                *(u16x4*)(dst + addr) = val;
            } else {
                const int h2 = m >> 6, dd = m & 63;
                const int bq = n0 >> 11, t = n0 & 2047;
                const size_t addr = (size_t)((bq * 16 + h2) * 64 + (t >> 5)) * 2048
                                  + (size_t)((dd >> 5) * 2 + ((t >> 4) & 1)) * 512
                                  + (size_t)((t >> 3) & 1) * 256
                                  + (size_t)(dd & 31) * 8 + (t & 7);
                *(u16x4*)(vfr + addr) = val;
            }
        }
    }
}

// ---------------------------------------------------------------------------
// Kernel 2a: a_state — A_c = sum_s gamma^(64-u) K_s (x) V_s, per (bh,c).
// ---------------------------------------------------------------------------
__global__ __launch_bounds__(128) void a_state(
    const unsigned short* __restrict__ kfr, const unsigned short* __restrict__ vfr,
    const float* __restrict__ gammas, unsigned short* __restrict__ states)
{
    __shared__ unsigned short kbuf[4096];

    const int bid = blockIdx.x;
    const int bh = bid & 31, c = bid >> 5;
    const int b = bh >> 4, h = bh & 15;
    const float lg = log2f(gammas[h]);
    const float gi1 = exp2f(-lg);

    const int tid = threadIdx.x;
    const int l = tid & 63, w = tid >> 6;
    const int l31 = l & 31, hi = l >> 5;

    const size_t hbase = (size_t)((b * 16 + h) * 64) * 2048;
    const unsigned short* src = kfr + hbase + (size_t)c * 4096;
    #pragma unroll
    for (int p = 0; p < 4; ++p)
        gl16(src + (w * 4 + p) * 512 + l * 8, kbuf + (w * 4 + p) * 512 + l * 8);
    asm volatile("s_waitcnt vmcnt(0)" ::: "memory");
    __builtin_amdgcn_s_barrier();
    __builtin_amdgcn_sched_barrier(0);

    const unsigned short* vfb = vfr + hbase + l * 8;
    const int dd = 32 * w + l31;
    const int dbase = (dd >> 4) * 512 + ((dd >> 3) & 1) * 256 + (dd & 7);

    f32x16 as0 = {}, as1 = {};
    #pragma unroll
    for (int sl = 0; sl < 2; ++sl) {
        bf16x8 vc[4];
        #pragma unroll
        for (int i = 0; i < 4; ++i)
            vc[i] = *(const bf16x8*)(vfb + (size_t)(2 * c + sl) * 2048 + i * 512);
        bf16x8 kt[2];
        #pragma unroll
        for (int kti = 0; kti < 2; ++kti) {
            float fac = exp2f(lg * (float)(64 - (32 * sl + 16 * kti + 8 * hi)));
            unsigned pk[4];
            #pragma unroll
            for (int jj = 0; jj < 4; ++jj) {
                const int s0 = 16 * kti + 8 * hi + 2 * jj;
                float e0 = bf2f(kbuf[sl * 2048 + dbase + s0 * 8]) * fac;
                fac *= gi1;
                float e1 = bf2f(kbuf[sl * 2048 + dbase + (s0 + 1) * 8]) * fac;
                fac *= gi1;
                pk[jj] = cvtpk(e0, e1);
            }
            u32x4 kv_ = { pk[0], pk[1], pk[2], pk[3] };
            kt[kti] = __builtin_bit_cast(bf16x8, kv_);
        }
        as0 = mfma32(kt[0], vc[0], as0);
        as0 = mfma32(kt[1], vc[1], as0);
        as1 = mfma32(kt[0], vc[2], as1);
        as1 = mfma32(kt[1], vc[3], as1);
    }

    unsigned short* sbase = states + (size_t)(bh * 32 + c) * 4096;
    #pragma unroll
    for (int r = 0; r < 16; ++r) {
        const int crow = (r & 3) + (hi << 2) + ((r >> 2) << 3);
        const size_t a = (size_t)(2 * w + (crow >> 4)) * 1024
                       + (size_t)((crow >> 3) & 1) * 256 + (crow & 7) + (size_t)l31 * 8;
        sbase[a]       = f2bf(as0[r]);
        sbase[a + 512] = f2bf(as1[r]);
    }
}

// ---------------------------------------------------------------------------
// Kernel 2b: state_scan — per (bh): S_c = gamma^64 S_{c-1} + A_c, in place.
// ---------------------------------------------------------------------------
__global__ __launch_bounds__(256) void state_scan(
    unsigned short* __restrict__ states, const float* __restrict__ gammas)
{
    const int bh = blockIdx.x;
    const float g64 = exp2f(64.0f * log2f(gammas[bh & 15]));
    unsigned short* base = states + (size_t)bh * 32 * 4096 + threadIdx.x * 16;

    float S[16] = {};
    u16x8 a0 = *(const u16x8*)(base);
    u16x8 a1 = *(const u16x8*)(base + 8);
    for (int c = 0; c < 32; ++c) {
        u16x8 n0, n1;
        if (c + 1 < 32) {
            n0 = *(const u16x8*)(base + (size_t)(c + 1) * 4096);
            n1 = *(const u16x8*)(base + (size_t)(c + 1) * 4096 + 8);
        }
        u16x8 o0, o1;
        #pragma unroll
        for (int e = 0; e < 8; ++e) {
            S[e] = S[e] * g64 + bf2f(a0[e]);
            o0[e] = f2bf(S[e]);
        }
        #pragma unroll
        for (int e = 0; e < 8; ++e) {
            S[8 + e] = S[8 + e] * g64 + bf2f(a1[e]);
            o1[e] = f2bf(S[8 + e]);
        }
        *(u16x8*)(base + (size_t)c * 4096) = o0;
        *(u16x8*)(base + (size_t)c * 4096 + 8) = o1;
        a0 = n0; a1 = n1;
    }
}

// ---------------------------------------------------------------------------
// Kernel 2c: chunk_out — inter (Q@S_{c-1}) + intra causal, single store.
// ---------------------------------------------------------------------------
__global__ __launch_bounds__(128) void chunk_out(
    const unsigned short* __restrict__ qfr, const unsigned short* __restrict__ kfr,
    const unsigned short* __restrict__ vfr, const unsigned short* __restrict__ states,
    const float* __restrict__ gammas, unsigned short* __restrict__ ret)
{
    const int bid = blockIdx.x;
    const int bh = bid & 31, c = bid >> 5;
    const int b = bh >> 4, h = bh & 15;
    const float lg = log2f(gammas[h]);

    const int tid = threadIdx.x;
    const int l = tid & 63, w = tid >> 6;
    const int l31 = l & 31, hi = l >> 5;
    const int gt = 2 * c + w;

    const size_t hbase = (size_t)((b * 16 + h) * 64) * 2048;
    const unsigned short* qfb = qfr + hbase + l * 8;
    const unsigned short* kfb = kfr + hbase + l * 8;
    const unsigned short* vfb = vfr + hbase + l * 8;

    bf16x8 qf[4];
    #pragma unroll
    for (int kt = 0; kt < 4; ++kt)
        qf[kt] = *(const bf16x8*)(qfb + (size_t)gt * 2048 + kt * 512);

    f32x16 acc0 = {}, acc1 = {};

    if (c > 0) {
        const unsigned short* sb_ = states + (size_t)(bh * 32 + c - 1) * 4096 + l * 8;
        bf16x8 sf[4][2];
        #pragma unroll
        for (int kt = 0; kt < 4; ++kt)
            #pragma unroll
            for (int dh = 0; dh < 2; ++dh)
                sf[kt][dh] = *(const bf16x8*)(sb_ + kt * 1024 + dh * 512);
        f32x16 a0 = {}, a1 = {};
        #pragma unroll
        for (int kt = 0; kt < 4; ++kt) {
            a0 = mfma32(qf[kt], sf[kt][0], a0);
            a1 = mfma32(qf[kt], sf[kt][1], a1);
        }
        #pragma unroll
        for (int r = 0; r < 16; ++r) {
            const int crow = (r & 3) + (hi << 2) + ((r >> 2) << 3);
            const float sfac = 0.125f * exp2f(lg * (float)(32 * w + crow));
            acc0[r] = a0[r] * sfac;
            acc1[r] = a1[r] * sfac;
        }
    }

    float cf[16];
    #pragma unroll
    for (int r = 0; r < 16; ++r) {
        const int crow = (r & 3) + (hi << 2) + ((r >> 2) << 3);
        cf[r] = exp2f((float)(31 - crow) * lg);
    }
    for (int sl = 0; sl <= w; ++sl) {
        const int gs = 2 * c + sl;
        bf16x8 kc[4], vc[4];
        #pragma unroll
        for (int kt = 0; kt < 4; ++kt)
            kc[kt] = *(const bf16x8*)(kfb + (size_t)gs * 2048 + kt * 512);
        #pragma unroll
        for (int i = 0; i < 4; ++i)
            vc[i] = *(const bf16x8*)(vfb + (size_t)gs * 2048 + i * 512);

        f32x16 sc = {};
        #pragma unroll
        for (int kt = 0; kt < 4; ++kt) sc = mfma32(kc[kt], qf[kt], sc);

        const float rowf = 0.125f * exp2f((float)((w - sl) * 32 + l31 - 31) * lg);
        float wv_[16];
        if (sl == w) {
            #pragma unroll
            for (int r = 0; r < 16; ++r) {
                const int crow = (r & 3) + (hi << 2) + ((r >> 2) << 3);
                float t_ = sc[r] * rowf * cf[r];
                wv_[r] = (l31 >= crow) ? t_ : 0.0f;
            }
        } else {
            #pragma unroll
            for (int r = 0; r < 16; ++r) wv_[r] = sc[r] * rowf * cf[r];
        }
        unsigned pk_[8];
        #pragma unroll
        for (int i = 0; i < 8; ++i) pk_[i] = cvtpk(wv_[2 * i], wv_[2 * i + 1]);
        asm("v_permlane32_swap_b32 %0, %1" : "+v"(pk_[0]), "+v"(pk_[2]));
        asm("v_permlane32_swap_b32 %0, %1" : "+v"(pk_[1]), "+v"(pk_[3]));
        asm("v_permlane32_swap_b32 %0, %1" : "+v"(pk_[4]), "+v"(pk_[6]));
        asm("v_permlane32_swap_b32 %0, %1" : "+v"(pk_[5]), "+v"(pk_[7]));
        u32x4 f0v = { pk_[0], pk_[1], pk_[2], pk_[3] };
        u32x4 f1v = { pk_[4], pk_[5], pk_[6], pk_[7] };
        const bf16x8 pa0 = __builtin_bit_cast(bf16x8, f0v);
        const bf16x8 pa1 = __builtin_bit_cast(bf16x8, f1v);
        acc0 = mfma32(pa0, vc[0], acc0);
        acc0 = mfma32(pa1, vc[1], acc0);
        acc1 = mfma32(pa0, vc[2], acc1);
        acc1 = mfma32(pa1, vc[3], acc1);
    }

    #pragma unroll
    for (int r = 0; r < 16; ++r) {
        const int tl = (r & 3) + (hi << 2) + ((r >> 2) << 3);
        unsigned short* dst = ret + (size_t)(b * 2048 + gt * 32 + tl) * 1024 + h * 64 + l31;
        dst[0]  = f2bf(acc0[r]);
        dst[32] = f2bf(acc1[r]);
    }
}

// ---------------------------------------------------------------------------
// Kernel 3: out = ret @ wo.T, prefetch-overlap 2-phase (R21 version).
// ---------------------------------------------------------------------------
__global__ __launch_bounds__(256) void out_bf16(
    const unsigned short* __restrict__ ret, const unsigned short* __restrict__ wob,
    float* __restrict__ out)
{
    __shared__ unsigned short sR[128 * 64];
    __shared__ unsigned short sL[128 * 64];

    const int rblk = blockIdx.x;
    const int lblk = blockIdx.y;

    const int tid = threadIdx.x;
    const int l = tid & 63, w = tid >> 6;
    const int lrow = l & 15, koff4 = (l >> 4) * 4;
    const int swz = lrow & 7;
    const int wrow = (w >> 1) * 64, wcol = (w & 1) * 64;

    f32x4 acc[4][4] = {};

    const int srow = w * 32 + (l >> 3);
    const int scol = ((l & 7) ^ ((l >> 3) & 7)) * 8;
    const unsigned short* gR = ret + (size_t)(rblk * 128 + srow) * 1024 + scol;
    const unsigned short* gL = wob + (size_t)(lblk * 128 + srow) * 1024 + scol;
    unsigned short* lRb = sR + (w * 32) * 64;
    unsigned short* lLb = sL + (w * 32) * 64;

    auto stage = [&](int kk) {
        #pragma unroll
        for (int p = 0; p < 4; ++p) {
            gl16(gR + (size_t)p * 8 * 1024 + kk, lRb + p * 512);
            gl16(gL + (size_t)p * 8 * 1024 + kk, lLb + p * 512);
        }
    };

    stage(0);
    for (int kk = 0; kk < 1024; kk += 64) {
        asm volatile("s_waitcnt vmcnt(0)" ::: "memory");
        __builtin_amdgcn_s_barrier();
        __builtin_amdgcn_sched_barrier(0);

        bf16x8 aL[2][4], bR[2][4];
        #pragma unroll
        for (int kt = 0; kt < 2; ++kt)
            #pragma unroll
            for (int f = 0; f < 4; ++f) {
                const int co = ((kt * 4 + (l >> 4)) ^ swz) * 8;
                aL[kt][f] = *(const bf16x8*)&sL[(wcol + f * 16 + lrow) * 64 + co];
                bR[kt][f] = *(const bf16x8*)&sR[(wrow + f * 16 + lrow) * 64 + co];
            }
        asm volatile("s_waitcnt lgkmcnt(0)" ::: "memory");
        __builtin_amdgcn_sched_barrier(0);
        __builtin_amdgcn_s_barrier();
        __builtin_amdgcn_sched_barrier(0);

        if (kk + 64 < 1024) stage(kk + 64);

        __builtin_amdgcn_s_setprio(1);
        #pragma unroll
        for (int kt = 0; kt < 2; ++kt)
            #pragma unroll
            for (int af = 0; af < 4; ++af)
                #pragma unroll
                for (int bf = 0; bf < 4; ++bf)
                    acc[af][bf] = mfma16(aL[kt][af], bR[kt][bf], acc[af][bf]);
        __builtin_amdgcn_s_setprio(0);
    }

    #pragma unroll
    for (int af = 0; af < 4; ++af)
        #pragma unroll
        for (int bf = 0; bf < 4; ++bf) {
            const int m = rblk * 128 + wrow + bf * 16 + lrow;
            const int n0 = lblk * 128 + wcol + af * 16 + koff4;
            *(f32x4*)(out + (size_t)m * 1024 + n0) = acc[af][bf];
        }
}

extern "C" void kernel_launch(void* const* d_in, const int* in_sizes, int n_in,
                              void* d_out, int out_size, void* d_ws, size_t ws_size,
                              hipStream_t stream) {
    const float* x      = (const float*)d_in[0];
    const float* wq     = (const float*)d_in[1];
    const float* wk     = (const float*)d_in[2];
    const float* wv     = (const float*)d_in[3];
    const float* wo     = (const float*)d_in[4];
    const float* gammas = (const float*)d_in[5];
    float* out = (float*)d_out;

    unsigned short* ws = (unsigned short*)d_ws;
    const size_t M = 1024 * 1024;
    unsigned short* qf     = ws;
    unsigned short* kf     = ws + 4 * M;
    unsigned short* vf     = ws + 8 * M;
    unsigned short* ret    = ws + 12 * M;    // also xb (dead after qkv)
    unsigned short* xb     = ret;
    unsigned short* wqb    = ws + 16 * M;
    unsigned short* wkb    = ws + 17 * M;
    unsigned short* wvb    = ws + 18 * M;
    unsigned short* states = ws + 16 * M;    // aliases wq/wk/wv (dead after qkv)
    unsigned short* wob    = ws + 20 * M;    // OUTSIDE the states alias region

    convert_bf16<<<1024, 256, 0, stream>>>(x, wq, wk, wv, wo, xb, wqb, wkb, wvb, wob);
    qkv_bf16<<<dim3(16, 4, 3), 512, 0, stream>>>(xb, wqb, wkb, wvb, qf, kf, vf);
    a_state<<<1024, 128, 0, stream>>>(kf, vf, gammas, states);
    state_scan<<<32, 256, 0, stream>>>(states, gammas);
    chunk_out<<<1024, 128, 0, stream>>>(qf, kf, vf, states, gammas, ret);
    out_bf16<<<dim3(32, 8), 256, 0, stream>>>(ret, wob, out);
}

// Round 24
// 81.945 us; speedup vs baseline: 1.1164x; 1.1164x over previous
//
#include <hip/hip_runtime.h>

// MultiScaleRetention on MI355X (gfx950) — chunked-state formulation v2.
// R21 configuration + state_scan parallelized 32 -> 128 blocks.
// B=2, L=2048, D=1024, H=16, hd=64. fp32 in/out, bf16 MFMA internally.
//
// ws layout (ushort elems), 42 MB:
//   qf[0..4M) | kf[4M..8M) | vf[8M..12M) | ret/xb[12M..16M) |
//   wqb[16M..17M) wkb[17M..18M) wvb[18M..19M) spare | wob[20M..21M)
//   states (4M ushorts = 8MB) ALIASES [16M..20M) (weights dead after qkv)

typedef __attribute__((ext_vector_type(8))) short bf16x8;
typedef __attribute__((ext_vector_type(4))) float f32x4;
typedef __attribute__((ext_vector_type(16))) float f32x16;
typedef __attribute__((ext_vector_type(4))) unsigned short u16x4;
typedef __attribute__((ext_vector_type(8))) unsigned short u16x8;
typedef __attribute__((ext_vector_type(4))) unsigned int u32x4;

__device__ inline unsigned short f2bf(float f) {
    unsigned int u;
    __builtin_memcpy(&u, &f, 4);
    u += 0x7fffu + ((u >> 16) & 1u);
    return (unsigned short)(u >> 16);
}
__device__ inline float bf2f(unsigned short us) {
    unsigned int u = (unsigned int)us << 16;
    float f;
    __builtin_memcpy(&f, &u, 4);
    return f;
}

__device__ inline f32x4 mfma16(bf16x8 a, bf16x8 b, f32x4 c) {
    return __builtin_amdgcn_mfma_f32_16x16x32_bf16(a, b, c, 0, 0, 0);
}
__device__ inline f32x16 mfma32(bf16x8 a, bf16x8 b, f32x16 c) {
    return __builtin_amdgcn_mfma_f32_32x32x16_bf16(a, b, c, 0, 0, 0);
}

__device__ inline void gl16(const unsigned short* g, unsigned short* l) {
    __builtin_amdgcn_global_load_lds(
        (const __attribute__((address_space(1))) unsigned int*)g,
        (__attribute__((address_space(3))) unsigned int*)l,
        16, 0, 0);
}

__device__ inline unsigned cvtpk(float lo, float hi) {
    unsigned r;
    asm("v_cvt_pk_bf16_f32 %0, %1, %2" : "=v"(r) : "v"(lo), "v"(hi));
    return r;
}

// ---------------------------------------------------------------------------
// Kernel 0: f32 -> bf16 conversion of x and the four weight matrices.
// ---------------------------------------------------------------------------
__global__ __launch_bounds__(256) void convert_bf16(
    const float* __restrict__ x,
    const float* __restrict__ wq, const float* __restrict__ wk,
    const float* __restrict__ wv, const float* __restrict__ wo,
    unsigned short* __restrict__ xb,
    unsigned short* __restrict__ wqb, unsigned short* __restrict__ wkb,
    unsigned short* __restrict__ wvb, unsigned short* __restrict__ wob)
{
    int cid = blockIdx.x * 256 + threadIdx.x;
    #pragma unroll
    for (int it = 0; it < 4; ++it, cid += 262144) {
        const float* src;
        unsigned short* dst;
        size_t off;
        if (cid < 524288) {
            src = x; dst = xb; off = (size_t)cid * 8;
        } else {
            const int t = cid - 524288;
            const int seg = t >> 17;
            off = (size_t)(t & 131071) * 8;
            src = seg == 0 ? wq : seg == 1 ? wk : seg == 2 ? wv : wo;
            dst = seg == 0 ? wqb : seg == 1 ? wkb : seg == 2 ? wvb : wob;
        }
        f32x4 a = *(const f32x4*)(src + off);
        f32x4 b = *(const f32x4*)(src + off + 4);
        u32x4 v = { cvtpk(a[0], a[1]), cvtpk(a[2], a[3]),
                    cvtpk(b[0], b[1]), cvtpk(b[2], b[3]) };
        *(u32x4*)(dst + off) = v;
    }
}

// ---------------------------------------------------------------------------
// Kernel 1: QKV projections, prefetch-overlap 2-phase (R21/R14 version —
// defended by 6 failed restructures; do not touch).
// ---------------------------------------------------------------------------
__global__ __launch_bounds__(256) void qkv_bf16(
    const unsigned short* __restrict__ xb,
    const unsigned short* __restrict__ wqb, const unsigned short* __restrict__ wkb,
    const unsigned short* __restrict__ wvb,
    unsigned short* __restrict__ qfr, unsigned short* __restrict__ kfr,
    unsigned short* __restrict__ vfr)
{
    __shared__ unsigned short sR[128 * 64];
    __shared__ unsigned short sL[128 * 64];

    const int z = blockIdx.z;
    const unsigned short* W = (z == 0) ? wqb : (z == 1) ? wkb : wvb;
    const unsigned short* Rs = (z < 2) ? xb : W;
    const unsigned short* Ls = (z < 2) ? W : xb;
    const int rblk = (z < 2) ? blockIdx.x : blockIdx.y;
    const int lblk = (z < 2) ? blockIdx.y : blockIdx.x;

    const int tid = threadIdx.x;
    const int l = tid & 63, w = tid >> 6;
    const int lrow = l & 15, koff4 = (l >> 4) * 4;
    const int swz = lrow & 7;
    const int wrow = (w >> 1) * 64, wcol = (w & 1) * 64;

    f32x4 acc[4][4] = {};

    const int srow = w * 32 + (l >> 3);
    const int scol = ((l & 7) ^ ((l >> 3) & 7)) * 8;
    const unsigned short* gR = Rs + (size_t)(rblk * 128 + srow) * 1024 + scol;
    const unsigned short* gL = Ls + (size_t)(lblk * 128 + srow) * 1024 + scol;
    unsigned short* lRb = sR + (w * 32) * 64;
    unsigned short* lLb = sL + (w * 32) * 64;

    auto stage = [&](int kk) {
        #pragma unroll
        for (int p = 0; p < 4; ++p) {
            gl16(gR + (size_t)p * 8 * 1024 + kk, lRb + p * 512);
            gl16(gL + (size_t)p * 8 * 1024 + kk, lLb + p * 512);
        }
    };

    stage(0);
    for (int kk = 0; kk < 1024; kk += 64) {
        asm volatile("s_waitcnt vmcnt(0)" ::: "memory");
        __builtin_amdgcn_s_barrier();
        __builtin_amdgcn_sched_barrier(0);

        bf16x8 aL[2][4], bR[2][4];
        #pragma unroll
        for (int kt = 0; kt < 2; ++kt)
            #pragma unroll
            for (int f = 0; f < 4; ++f) {
                const int co = ((kt * 4 + (l >> 4)) ^ swz) * 8;
                aL[kt][f] = *(const bf16x8*)&sL[(wcol + f * 16 + lrow) * 64 + co];
                bR[kt][f] = *(const bf16x8*)&sR[(wrow + f * 16 + lrow) * 64 + co];
            }
        asm volatile("s_waitcnt lgkmcnt(0)" ::: "memory");
        __builtin_amdgcn_sched_barrier(0);
        __builtin_amdgcn_s_barrier();
        __builtin_amdgcn_sched_barrier(0);

        if (kk + 64 < 1024) stage(kk + 64);

        __builtin_amdgcn_s_setprio(1);
        #pragma unroll
        for (int kt = 0; kt < 2; ++kt)
            #pragma unroll
            for (int af = 0; af < 4; ++af)
                #pragma unroll
                for (int bf = 0; bf < 4; ++bf)
                    acc[af][bf] = mfma16(aL[kt][af], bR[kt][bf], acc[af][bf]);
        __builtin_amdgcn_s_setprio(0);
    }

    #pragma unroll
    for (int af = 0; af < 4; ++af) {
        #pragma unroll
        for (int bf = 0; bf < 4; ++bf) {
            const int m = rblk * 128 + wrow + bf * 16 + lrow;
            const int n0 = lblk * 128 + wcol + af * 16 + koff4;
            f32x4 v = acc[af][bf];
            unsigned p0 = cvtpk(v[0], v[1]), p1 = cvtpk(v[2], v[3]);
            u16x4 val = { (unsigned short)(p0 & 0xffff), (unsigned short)(p0 >> 16),
                          (unsigned short)(p1 & 0xffff), (unsigned short)(p1 >> 16) };
            if (z < 2) {
                const int bq = m >> 11, s = m & 2047;
                const int h2 = n0 >> 6, dd = n0 & 63;
                const size_t addr = (size_t)((bq * 16 + h2) * 64 + (s >> 5)) * 2048
                                  + (size_t)(dd >> 4) * 512 + (size_t)((dd >> 3) & 1) * 256
                                  + (size_t)(s & 31) * 8 + (dd & 7);
                unsigned short* dst = z ? kfr : qfr;
                *(u16x4*)(dst + addr) = val;
            } else {
                const int h2 = m >> 6, dd = m & 63;
                const int bq = n0 >> 11, t = n0 & 2047;
                const size_t addr = (size_t)((bq * 16 + h2) * 64 + (t >> 5)) * 2048
                                  + (size_t)((dd >> 5) * 2 + ((t >> 4) & 1)) * 512
                                  + (size_t)((t >> 3) & 1) * 256
                                  + (size_t)(dd & 31) * 8 + (t & 7);
                *(u16x4*)(vfr + addr) = val;
            }
        }
    }
}

// ---------------------------------------------------------------------------
// Kernel 2a: a_state — A_c = sum_s gamma^(64-u) K_s (x) V_s, per (bh,c).
// ---------------------------------------------------------------------------
__global__ __launch_bounds__(128) void a_state(
    const unsigned short* __restrict__ kfr, const unsigned short* __restrict__ vfr,
    const float* __restrict__ gammas, unsigned short* __restrict__ states)
{
    __shared__ unsigned short kbuf[4096];

    const int bid = blockIdx.x;
    const int bh = bid & 31, c = bid >> 5;
    const int b = bh >> 4, h = bh & 15;
    const float lg = log2f(gammas[h]);
    const float gi1 = exp2f(-lg);

    const int tid = threadIdx.x;
    const int l = tid & 63, w = tid >> 6;
    const int l31 = l & 31, hi = l >> 5;

    const size_t hbase = (size_t)((b * 16 + h) * 64) * 2048;
    const unsigned short* src = kfr + hbase + (size_t)c * 4096;
    #pragma unroll
    for (int p = 0; p < 4; ++p)
        gl16(src + (w * 4 + p) * 512 + l * 8, kbuf + (w * 4 + p) * 512 + l * 8);
    asm volatile("s_waitcnt vmcnt(0)" ::: "memory");
    __builtin_amdgcn_s_barrier();
    __builtin_amdgcn_sched_barrier(0);

    const unsigned short* vfb = vfr + hbase + l * 8;
    const int dd = 32 * w + l31;
    const int dbase = (dd >> 4) * 512 + ((dd >> 3) & 1) * 256 + (dd & 7);

    f32x16 as0 = {}, as1 = {};
    #pragma unroll
    for (int sl = 0; sl < 2; ++sl) {
        bf16x8 vc[4];
        #pragma unroll
        for (int i = 0; i < 4; ++i)
            vc[i] = *(const bf16x8*)(vfb + (size_t)(2 * c + sl) * 2048 + i * 512);
        bf16x8 kt[2];
        #pragma unroll
        for (int kti = 0; kti < 2; ++kti) {
            float fac = exp2f(lg * (float)(64 - (32 * sl + 16 * kti + 8 * hi)));
            unsigned pk[4];
            #pragma unroll
            for (int jj = 0; jj < 4; ++jj) {
                const int s0 = 16 * kti + 8 * hi + 2 * jj;
                float e0 = bf2f(kbuf[sl * 2048 + dbase + s0 * 8]) * fac;
                fac *= gi1;
                float e1 = bf2f(kbuf[sl * 2048 + dbase + (s0 + 1) * 8]) * fac;
                fac *= gi1;
                pk[jj] = cvtpk(e0, e1);
            }
            u32x4 kv_ = { pk[0], pk[1], pk[2], pk[3] };
            kt[kti] = __builtin_bit_cast(bf16x8, kv_);
        }
        as0 = mfma32(kt[0], vc[0], as0);
        as0 = mfma32(kt[1], vc[1], as0);
        as1 = mfma32(kt[0], vc[2], as1);
        as1 = mfma32(kt[1], vc[3], as1);
    }

    unsigned short* sbase = states + (size_t)(bh * 32 + c) * 4096;
    #pragma unroll
    for (int r = 0; r < 16; ++r) {
        const int crow = (r & 3) + (hi << 2) + ((r >> 2) << 3);
        const size_t a = (size_t)(2 * w + (crow >> 4)) * 1024
                       + (size_t)((crow >> 3) & 1) * 256 + (crow & 7) + (size_t)l31 * 8;
        sbase[a]       = f2bf(as0[r]);
        sbase[a + 512] = f2bf(as1[r]);
    }
}

// ---------------------------------------------------------------------------
// Kernel 2b: state_scan — per (bh): S_c = gamma^64 S_{c-1} + A_c, in place.
// PARALLELIZED: 128 blocks (4 per bh), each thread owns 4 elems (u16x4).
// Same math / same order as the 32-block version -> bit-identical states.
// ---------------------------------------------------------------------------
__global__ __launch_bounds__(256) void state_scan(
    unsigned short* __restrict__ states, const float* __restrict__ gammas)
{
    const int bh = blockIdx.x >> 2;
    const int part = blockIdx.x & 3;
    const float g64 = exp2f(64.0f * log2f(gammas[bh & 15]));
    unsigned short* base = states + (size_t)bh * 32 * 4096
                         + (size_t)part * 1024 + threadIdx.x * 4;

    float S[4] = {};
    u16x4 a0 = *(const u16x4*)(base);
    for (int c = 0; c < 32; ++c) {
        u16x4 n0;
        if (c + 1 < 32)
            n0 = *(const u16x4*)(base + (size_t)(c + 1) * 4096);
        u16x4 o0;
        #pragma unroll
        for (int e = 0; e < 4; ++e) {
            S[e] = S[e] * g64 + bf2f(a0[e]);
            o0[e] = f2bf(S[e]);
        }
        *(u16x4*)(base + (size_t)c * 4096) = o0;
        a0 = n0;
    }
}

// ---------------------------------------------------------------------------
// Kernel 2c: chunk_out — inter (Q@S_{c-1}) + intra causal, single store.
// ---------------------------------------------------------------------------
__global__ __launch_bounds__(128) void chunk_out(
    const unsigned short* __restrict__ qfr, const unsigned short* __restrict__ kfr,
    const unsigned short* __restrict__ vfr, const unsigned short* __restrict__ states,
    const float* __restrict__ gammas, unsigned short* __restrict__ ret)
{
    const int bid = blockIdx.x;
    const int bh = bid & 31, c = bid >> 5;
    const int b = bh >> 4, h = bh & 15;
    const float lg = log2f(gammas[h]);

    const int tid = threadIdx.x;
    const int l = tid & 63, w = tid >> 6;
    const int l31 = l & 31, hi = l >> 5;
    const int gt = 2 * c + w;

    const size_t hbase = (size_t)((b * 16 + h) * 64) * 2048;
    const unsigned short* qfb = qfr + hbase + l * 8;
    const unsigned short* kfb = kfr + hbase + l * 8;
    const unsigned short* vfb = vfr + hbase + l * 8;

    bf16x8 qf[4];
    #pragma unroll
    for (int kt = 0; kt < 4; ++kt)
        qf[kt] = *(const bf16x8*)(qfb + (size_t)gt * 2048 + kt * 512);

    f32x16 acc0 = {}, acc1 = {};

    if (c > 0) {
        const unsigned short* sb_ = states + (size_t)(bh * 32 + c - 1) * 4096 + l * 8;
        bf16x8 sf[4][2];
        #pragma unroll
        for (int kt = 0; kt < 4; ++kt)
            #pragma unroll
            for (int dh = 0; dh < 2; ++dh)
                sf[kt][dh] = *(const bf16x8*)(sb_ + kt * 1024 + dh * 512);
        f32x16 a0 = {}, a1 = {};
        #pragma unroll
        for (int kt = 0; kt < 4; ++kt) {
            a0 = mfma32(qf[kt], sf[kt][0], a0);
            a1 = mfma32(qf[kt], sf[kt][1], a1);
        }
        #pragma unroll
        for (int r = 0; r < 16; ++r) {
            const int crow = (r & 3) + (hi << 2) + ((r >> 2) << 3);
            const float sfac = 0.125f * exp2f(lg * (float)(32 * w + crow));
            acc0[r] = a0[r] * sfac;
            acc1[r] = a1[r] * sfac;
        }
    }

    float cf[16];
    #pragma unroll
    for (int r = 0; r < 16; ++r) {
        const int crow = (r & 3) + (hi << 2) + ((r >> 2) << 3);
        cf[r] = exp2f((float)(31 - crow) * lg);
    }
    for (int sl = 0; sl <= w; ++sl) {
        const int gs = 2 * c + sl;
        bf16x8 kc[4], vc[4];
        #pragma unroll
        for (int kt = 0; kt < 4; ++kt)
            kc[kt] = *(const bf16x8*)(kfb + (size_t)gs * 2048 + kt * 512);
        #pragma unroll
        for (int i = 0; i < 4; ++i)
            vc[i] = *(const bf16x8*)(vfb + (size_t)gs * 2048 + i * 512);

        f32x16 sc = {};
        #pragma unroll
        for (int kt = 0; kt < 4; ++kt) sc = mfma32(kc[kt], qf[kt], sc);

        const float rowf = 0.125f * exp2f((float)((w - sl) * 32 + l31 - 31) * lg);
        float wv_[16];
        if (sl == w) {
            #pragma unroll
            for (int r = 0; r < 16; ++r) {
                const int crow = (r & 3) + (hi << 2) + ((r >> 2) << 3);
                float t_ = sc[r] * rowf * cf[r];
                wv_[r] = (l31 >= crow) ? t_ : 0.0f;
            }
        } else {
            #pragma unroll
            for (int r = 0; r < 16; ++r) wv_[r] = sc[r] * rowf * cf[r];
        }
        unsigned pk_[8];
        #pragma unroll
        for (int i = 0; i < 8; ++i) pk_[i] = cvtpk(wv_[2 * i], wv_[2 * i + 1]);
        asm("v_permlane32_swap_b32 %0, %1" : "+v"(pk_[0]), "+v"(pk_[2]));
        asm("v_permlane32_swap_b32 %0, %1" : "+v"(pk_[1]), "+v"(pk_[3]));
        asm("v_permlane32_swap_b32 %0, %1" : "+v"(pk_[4]), "+v"(pk_[6]));
        asm("v_permlane32_swap_b32 %0, %1" : "+v"(pk_[5]), "+v"(pk_[7]));
        u32x4 f0v = { pk_[0], pk_[1], pk_[2], pk_[3] };
        u32x4 f1v = { pk_[4], pk_[5], pk_[6], pk_[7] };
        const bf16x8 pa0 = __builtin_bit_cast(bf16x8, f0v);
        const bf16x8 pa1 = __builtin_bit_cast(bf16x8, f1v);
        acc0 = mfma32(pa0, vc[0], acc0);
        acc0 = mfma32(pa1, vc[1], acc0);
        acc1 = mfma32(pa0, vc[2], acc1);
        acc1 = mfma32(pa1, vc[3], acc1);
    }

    #pragma unroll
    for (int r = 0; r < 16; ++r) {
        const int tl = (r & 3) + (hi << 2) + ((r >> 2) << 3);
        unsigned short* dst = ret + (size_t)(b * 2048 + gt * 32 + tl) * 1024 + h * 64 + l31;
        dst[0]  = f2bf(acc0[r]);
        dst[32] = f2bf(acc1[r]);
    }
}

// ---------------------------------------------------------------------------
// Kernel 3: out = ret @ wo.T, prefetch-overlap 2-phase (R21 version).
// ---------------------------------------------------------------------------
__global__ __launch_bounds__(256) void out_bf16(
    const unsigned short* __restrict__ ret, const unsigned short* __restrict__ wob,
    float* __restrict__ out)
{
    __shared__ unsigned short sR[128 * 64];
    __shared__ unsigned short sL[128 * 64];

    const int rblk = blockIdx.x;
    const int lblk = blockIdx.y;

    const int tid = threadIdx.x;
    const int l = tid & 63, w = tid >> 6;
    const int lrow = l & 15, koff4 = (l >> 4) * 4;
    const int swz = lrow & 7;
    const int wrow = (w >> 1) * 64, wcol = (w & 1) * 64;

    f32x4 acc[4][4] = {};

    const int srow = w * 32 + (l >> 3);
    const int scol = ((l & 7) ^ ((l >> 3) & 7)) * 8;
    const unsigned short* gR = ret + (size_t)(rblk * 128 + srow) * 1024 + scol;
    const unsigned short* gL = wob + (size_t)(lblk * 128 + srow) * 1024 + scol;
    unsigned short* lRb = sR + (w * 32) * 64;
    unsigned short* lLb = sL + (w * 32) * 64;

    auto stage = [&](int kk) {
        #pragma unroll
        for (int p = 0; p < 4; ++p) {
            gl16(gR + (size_t)p * 8 * 1024 + kk, lRb + p * 512);
            gl16(gL + (size_t)p * 8 * 1024 + kk, lLb + p * 512);
        }
    };

    stage(0);
    for (int kk = 0; kk < 1024; kk += 64) {
        asm volatile("s_waitcnt vmcnt(0)" ::: "memory");
        __builtin_amdgcn_s_barrier();
        __builtin_amdgcn_sched_barrier(0);

        bf16x8 aL[2][4], bR[2][4];
        #pragma unroll
        for (int kt = 0; kt < 2; ++kt)
            #pragma unroll
            for (int f = 0; f < 4; ++f) {
                const int co = ((kt * 4 + (l >> 4)) ^ swz) * 8;
                aL[kt][f] = *(const bf16x8*)&sL[(wcol + f * 16 + lrow) * 64 + co];
                bR[kt][f] = *(const bf16x8*)&sR[(wrow + f * 16 + lrow) * 64 + co];
            }
        asm volatile("s_waitcnt lgkmcnt(0)" ::: "memory");
        __builtin_amdgcn_sched_barrier(0);
        __builtin_amdgcn_s_barrier();
        __builtin_amdgcn_sched_barrier(0);

        if (kk + 64 < 1024) stage(kk + 64);

        __builtin_amdgcn_s_setprio(1);
        #pragma unroll
        for (int kt = 0; kt < 2; ++kt)
            #pragma unroll
            for (int af = 0; af < 4; ++af)
                #pragma unroll
                for (int bf = 0; bf < 4; ++bf)
                    acc[af][bf] = mfma16(aL[kt][af], bR[kt][bf], acc[af][bf]);
        __builtin_amdgcn_s_setprio(0);
    }

    #pragma unroll
    for (int af = 0; af < 4; ++af)
        #pragma unroll
        for (int bf = 0; bf < 4; ++bf) {
            const int m = rblk * 128 + wrow + bf * 16 + lrow;
            const int n0 = lblk * 128 + wcol + af * 16 + koff4;
            *(f32x4*)(out + (size_t)m * 1024 + n0) = acc[af][bf];
        }
}

extern "C" void kernel_launch(void* const* d_in, const int* in_sizes, int n_in,
                              void* d_out, int out_size, void* d_ws, size_t ws_size,
                              hipStream_t stream) {
    const float* x      = (const float*)d_in[0];
    const float* wq     = (const float*)d_in[1];
    const float* wk     = (const float*)d_in[2];
    const float* wv     = (const float*)d_in[3];
    const float* wo     = (const float*)d_in[4];
    const float* gammas = (const float*)d_in[5];
    float* out = (float*)d_out;

    unsigned short* ws = (unsigned short*)d_ws;
    const size_t M = 1024 * 1024;
    unsigned short* qf     = ws;
    unsigned short* kf     = ws + 4 * M;
    unsigned short* vf     = ws + 8 * M;
    unsigned short* ret    = ws + 12 * M;    // also xb (dead after qkv)
    unsigned short* xb     = ret;
    unsigned short* wqb    = ws + 16 * M;
    unsigned short* wkb    = ws + 17 * M;
    unsigned short* wvb    = ws + 18 * M;
    unsigned short* states = ws + 16 * M;    // aliases wq/wk/wv (dead after qkv)
    unsigned short* wob    = ws + 20 * M;    // OUTSIDE the states alias region

    convert_bf16<<<1024, 256, 0, stream>>>(x, wq, wk, wv, wo, xb, wqb, wkb, wvb, wob);
    qkv_bf16<<<dim3(32, 8, 3), 256, 0, stream>>>(xb, wqb, wkb, wvb, qf, kf, vf);
    a_state<<<1024, 128, 0, stream>>>(kf, vf, gammas, states);
    state_scan<<<128, 256, 0, stream>>>(states, gammas);
    chunk_out<<<1024, 128, 0, stream>>>(qf, kf, vf, states, gammas, ret);
    out_bf16<<<dim3(32, 8), 256, 0, stream>>>(ret, wob, out);
}

// Round 26
// 81.734 us; speedup vs baseline: 1.1193x; 1.0026x over previous
//
#include <hip/hip_runtime.h>

// MultiScaleRetention on MI355X (gfx950) — chunked-state formulation v2.
// R24 configuration (verified best: 81.9 us, absmax 0.0234).
// B=2, L=2048, D=1024, H=16, hd=64. fp32 in/out, bf16 MFMA internally.
//
// ws layout (ushort elems), 42 MB:
//   qf[0..4M) | kf[4M..8M) | vf[8M..12M) | ret/xb[12M..16M) |
//   wqb[16M..17M) wkb[17M..18M) wvb[18M..19M) spare | wob[20M..21M)
//   states (4M ushorts = 8MB) ALIASES [16M..20M) (weights dead after qkv)

typedef __attribute__((ext_vector_type(8))) short bf16x8;
typedef __attribute__((ext_vector_type(4))) float f32x4;
typedef __attribute__((ext_vector_type(16))) float f32x16;
typedef __attribute__((ext_vector_type(4))) unsigned short u16x4;
typedef __attribute__((ext_vector_type(8))) unsigned short u16x8;
typedef __attribute__((ext_vector_type(4))) unsigned int u32x4;

__device__ inline unsigned short f2bf(float f) {
    unsigned int u;
    __builtin_memcpy(&u, &f, 4);
    u += 0x7fffu + ((u >> 16) & 1u);
    return (unsigned short)(u >> 16);
}
__device__ inline float bf2f(unsigned short us) {
    unsigned int u = (unsigned int)us << 16;
    float f;
    __builtin_memcpy(&f, &u, 4);
    return f;
}

__device__ inline f32x4 mfma16(bf16x8 a, bf16x8 b, f32x4 c) {
    return __builtin_amdgcn_mfma_f32_16x16x32_bf16(a, b, c, 0, 0, 0);
}
__device__ inline f32x16 mfma32(bf16x8 a, bf16x8 b, f32x16 c) {
    return __builtin_amdgcn_mfma_f32_32x32x16_bf16(a, b, c, 0, 0, 0);
}

__device__ inline void gl16(const unsigned short* g, unsigned short* l) {
    __builtin_amdgcn_global_load_lds(
        (const __attribute__((address_space(1))) unsigned int*)g,
        (__attribute__((address_space(3))) unsigned int*)l,
        16, 0, 0);
}

__device__ inline unsigned cvtpk(float lo, float hi) {
    unsigned r;
    asm("v_cvt_pk_bf16_f32 %0, %1, %2" : "=v"(r) : "v"(lo), "v"(hi));
    return r;
}

// ---------------------------------------------------------------------------
// Kernel 0: f32 -> bf16 conversion of x and the four weight matrices.
// ---------------------------------------------------------------------------
__global__ __launch_bounds__(256) void convert_bf16(
    const float* __restrict__ x,
    const float* __restrict__ wq, const float* __restrict__ wk,
    const float* __restrict__ wv, const float* __restrict__ wo,
    unsigned short* __restrict__ xb,
    unsigned short* __restrict__ wqb, unsigned short* __restrict__ wkb,
    unsigned short* __restrict__ wvb, unsigned short* __restrict__ wob)
{
    int cid = blockIdx.x * 256 + threadIdx.x;
    #pragma unroll
    for (int it = 0; it < 4; ++it, cid += 262144) {
        const float* src;
        unsigned short* dst;
        size_t off;
        if (cid < 524288) {
            src = x; dst = xb; off = (size_t)cid * 8;
        } else {
            const int t = cid - 524288;
            const int seg = t >> 17;
            off = (size_t)(t & 131071) * 8;
            src = seg == 0 ? wq : seg == 1 ? wk : seg == 2 ? wv : wo;
            dst = seg == 0 ? wqb : seg == 1 ? wkb : seg == 2 ? wvb : wob;
        }
        f32x4 a = *(const f32x4*)(src + off);
        f32x4 b = *(const f32x4*)(src + off + 4);
        u32x4 v = { cvtpk(a[0], a[1]), cvtpk(a[2], a[3]),
                    cvtpk(b[0], b[1]), cvtpk(b[2], b[3]) };
        *(u32x4*)(dst + off) = v;
    }
}

// ---------------------------------------------------------------------------
// Kernel 1: QKV projections, prefetch-overlap 2-phase (R21/R14 version —
// defended by 6 failed restructures; do not touch).
// ---------------------------------------------------------------------------
__global__ __launch_bounds__(256) void qkv_bf16(
    const unsigned short* __restrict__ xb,
    const unsigned short* __restrict__ wqb, const unsigned short* __restrict__ wkb,
    const unsigned short* __restrict__ wvb,
    unsigned short* __restrict__ qfr, unsigned short* __restrict__ kfr,
    unsigned short* __restrict__ vfr)
{
    __shared__ unsigned short sR[128 * 64];
    __shared__ unsigned short sL[128 * 64];

    const int z = blockIdx.z;
    const unsigned short* W = (z == 0) ? wqb : (z == 1) ? wkb : wvb;
    const unsigned short* Rs = (z < 2) ? xb : W;
    const unsigned short* Ls = (z < 2) ? W : xb;
    const int rblk = (z < 2) ? blockIdx.x : blockIdx.y;
    const int lblk = (z < 2) ? blockIdx.y : blockIdx.x;

    const int tid = threadIdx.x;
    const int l = tid & 63, w = tid >> 6;
    const int lrow = l & 15, koff4 = (l >> 4) * 4;
    const int swz = lrow & 7;
    const int wrow = (w >> 1) * 64, wcol = (w & 1) * 64;

    f32x4 acc[4][4] = {};

    const int srow = w * 32 + (l >> 3);
    const int scol = ((l & 7) ^ ((l >> 3) & 7)) * 8;
    const unsigned short* gR = Rs + (size_t)(rblk * 128 + srow) * 1024 + scol;
    const unsigned short* gL = Ls + (size_t)(lblk * 128 + srow) * 1024 + scol;
    unsigned short* lRb = sR + (w * 32) * 64;
    unsigned short* lLb = sL + (w * 32) * 64;

    auto stage = [&](int kk) {
        #pragma unroll
        for (int p = 0; p < 4; ++p) {
            gl16(gR + (size_t)p * 8 * 1024 + kk, lRb + p * 512);
            gl16(gL + (size_t)p * 8 * 1024 + kk, lLb + p * 512);
        }
    };

    stage(0);
    for (int kk = 0; kk < 1024; kk += 64) {
        asm volatile("s_waitcnt vmcnt(0)" ::: "memory");
        __builtin_amdgcn_s_barrier();
        __builtin_amdgcn_sched_barrier(0);

        bf16x8 aL[2][4], bR[2][4];
        #pragma unroll
        for (int kt = 0; kt < 2; ++kt)
            #pragma unroll
            for (int f = 0; f < 4; ++f) {
                const int co = ((kt * 4 + (l >> 4)) ^ swz) * 8;
                aL[kt][f] = *(const bf16x8*)&sL[(wcol + f * 16 + lrow) * 64 + co];
                bR[kt][f] = *(const bf16x8*)&sR[(wrow + f * 16 + lrow) * 64 + co];
            }
        asm volatile("s_waitcnt lgkmcnt(0)" ::: "memory");
        __builtin_amdgcn_sched_barrier(0);
        __builtin_amdgcn_s_barrier();
        __builtin_amdgcn_sched_barrier(0);

        if (kk + 64 < 1024) stage(kk + 64);

        __builtin_amdgcn_s_setprio(1);
        #pragma unroll
        for (int kt = 0; kt < 2; ++kt)
            #pragma unroll
            for (int af = 0; af < 4; ++af)
                #pragma unroll
                for (int bf = 0; bf < 4; ++bf)
                    acc[af][bf] = mfma16(aL[kt][af], bR[kt][bf], acc[af][bf]);
        __builtin_amdgcn_s_setprio(0);
    }

    #pragma unroll
    for (int af = 0; af < 4; ++af) {
        #pragma unroll
        for (int bf = 0; bf < 4; ++bf) {
            const int m = rblk * 128 + wrow + bf * 16 + lrow;
            const int n0 = lblk * 128 + wcol + af * 16 + koff4;
            f32x4 v = acc[af][bf];
            unsigned p0 = cvtpk(v[0], v[1]), p1 = cvtpk(v[2], v[3]);
            u16x4 val = { (unsigned short)(p0 & 0xffff), (unsigned short)(p0 >> 16),
                          (unsigned short)(p1 & 0xffff), (unsigned short)(p1 >> 16) };
            if (z < 2) {
                const int bq = m >> 11, s = m & 2047;
                const int h2 = n0 >> 6, dd = n0 & 63;
                const size_t addr = (size_t)((bq * 16 + h2) * 64 + (s >> 5)) * 2048
                                  + (size_t)(dd >> 4) * 512 + (size_t)((dd >> 3) & 1) * 256
                                  + (size_t)(s & 31) * 8 + (dd & 7);
                unsigned short* dst = z ? kfr : qfr;
                *(u16x4*)(dst + addr) = val;
            } else {
                const int h2 = m >> 6, dd = m & 63;
                const int bq = n0 >> 11, t = n0 & 2047;
                const size_t addr = (size_t)((bq * 16 + h2) * 64 + (t >> 5)) * 2048
                                  + (size_t)((dd >> 5) * 2 + ((t >> 4) & 1)) * 512
                                  + (size_t)((t >> 3) & 1) * 256
                                  + (size_t)(dd & 31) * 8 + (t & 7);
                *(u16x4*)(vfr + addr) = val;
            }
        }
    }
}

// ---------------------------------------------------------------------------
// Kernel 2a: a_state — A_c = sum_s gamma^(64-u) K_s (x) V_s, per (bh,c).
// ---------------------------------------------------------------------------
__global__ __launch_bounds__(128) void a_state(
    const unsigned short* __restrict__ kfr, const unsigned short* __restrict__ vfr,
    const float* __restrict__ gammas, unsigned short* __restrict__ states)
{
    __shared__ unsigned short kbuf[4096];

    const int bid = blockIdx.x;
    const int bh = bid & 31, c = bid >> 5;
    const int b = bh >> 4, h = bh & 15;
    const float lg = log2f(gammas[h]);
    const float gi1 = exp2f(-lg);

    const int tid = threadIdx.x;
    const int l = tid & 63, w = tid >> 6;
    const int l31 = l & 31, hi = l >> 5;

    const size_t hbase = (size_t)((b * 16 + h) * 64) * 2048;
    const unsigned short* src = kfr + hbase + (size_t)c * 4096;
    #pragma unroll
    for (int p = 0; p < 4; ++p)
        gl16(src + (w * 4 + p) * 512 + l * 8, kbuf + (w * 4 + p) * 512 + l * 8);
    asm volatile("s_waitcnt vmcnt(0)" ::: "memory");
    __builtin_amdgcn_s_barrier();
    __builtin_amdgcn_sched_barrier(0);

    const unsigned short* vfb = vfr + hbase + l * 8;
    const int dd = 32 * w + l31;
    const int dbase = (dd >> 4) * 512 + ((dd >> 3) & 1) * 256 + (dd & 7);

    f32x16 as0 = {}, as1 = {};
    #pragma unroll
    for (int sl = 0; sl < 2; ++sl) {
        bf16x8 vc[4];
        #pragma unroll
        for (int i = 0; i < 4; ++i)
            vc[i] = *(const bf16x8*)(vfb + (size_t)(2 * c + sl) * 2048 + i * 512);
        bf16x8 kt[2];
        #pragma unroll
        for (int kti = 0; kti < 2; ++kti) {
            float fac = exp2f(lg * (float)(64 - (32 * sl + 16 * kti + 8 * hi)));
            unsigned pk[4];
            #pragma unroll
            for (int jj = 0; jj < 4; ++jj) {
                const int s0 = 16 * kti + 8 * hi + 2 * jj;
                float e0 = bf2f(kbuf[sl * 2048 + dbase + s0 * 8]) * fac;
                fac *= gi1;
                float e1 = bf2f(kbuf[sl * 2048 + dbase + (s0 + 1) * 8]) * fac;
                fac *= gi1;
                pk[jj] = cvtpk(e0, e1);
            }
            u32x4 kv_ = { pk[0], pk[1], pk[2], pk[3] };
            kt[kti] = __builtin_bit_cast(bf16x8, kv_);
        }
        as0 = mfma32(kt[0], vc[0], as0);
        as0 = mfma32(kt[1], vc[1], as0);
        as1 = mfma32(kt[0], vc[2], as1);
        as1 = mfma32(kt[1], vc[3], as1);
    }

    unsigned short* sbase = states + (size_t)(bh * 32 + c) * 4096;
    #pragma unroll
    for (int r = 0; r < 16; ++r) {
        const int crow = (r & 3) + (hi << 2) + ((r >> 2) << 3);
        const size_t a = (size_t)(2 * w + (crow >> 4)) * 1024
                       + (size_t)((crow >> 3) & 1) * 256 + (crow & 7) + (size_t)l31 * 8;
        sbase[a]       = f2bf(as0[r]);
        sbase[a + 512] = f2bf(as1[r]);
    }
}

// ---------------------------------------------------------------------------
// Kernel 2b: state_scan — per (bh): S_c = gamma^64 S_{c-1} + A_c, in place.
// PARALLELIZED: 128 blocks (4 per bh), each thread owns 4 elems (u16x4).
// ---------------------------------------------------------------------------
__global__ __launch_bounds__(256) void state_scan(
    unsigned short* __restrict__ states, const float* __restrict__ gammas)
{
    const int bh = blockIdx.x >> 2;
    const int part = blockIdx.x & 3;
    const float g64 = exp2f(64.0f * log2f(gammas[bh & 15]));
    unsigned short* base = states + (size_t)bh * 32 * 4096
                         + (size_t)part * 1024 + threadIdx.x * 4;

    float S[4] = {};
    u16x4 a0 = *(const u16x4*)(base);
    for (int c = 0; c < 32; ++c) {
        u16x4 n0;
        if (c + 1 < 32)
            n0 = *(const u16x4*)(base + (size_t)(c + 1) * 4096);
        u16x4 o0;
        #pragma unroll
        for (int e = 0; e < 4; ++e) {
            S[e] = S[e] * g64 + bf2f(a0[e]);
            o0[e] = f2bf(S[e]);
        }
        *(u16x4*)(base + (size_t)c * 4096) = o0;
        a0 = n0;
    }
}

// ---------------------------------------------------------------------------
// Kernel 2c: chunk_out — inter (Q@S_{c-1}) + intra causal, single store.
// ---------------------------------------------------------------------------
__global__ __launch_bounds__(128) void chunk_out(
    const unsigned short* __restrict__ qfr, const unsigned short* __restrict__ kfr,
    const unsigned short* __restrict__ vfr, const unsigned short* __restrict__ states,
    const float* __restrict__ gammas, unsigned short* __restrict__ ret)
{
    const int bid = blockIdx.x;
    const int bh = bid & 31, c = bid >> 5;
    const int b = bh >> 4, h = bh & 15;
    const float lg = log2f(gammas[h]);

    const int tid = threadIdx.x;
    const int l = tid & 63, w = tid >> 6;
    const int l31 = l & 31, hi = l >> 5;
    const int gt = 2 * c + w;

    const size_t hbase = (size_t)((b * 16 + h) * 64) * 2048;
    const unsigned short* qfb = qfr + hbase + l * 8;
    const unsigned short* kfb = kfr + hbase + l * 8;
    const unsigned short* vfb = vfr + hbase + l * 8;

    bf16x8 qf[4];
    #pragma unroll
    for (int kt = 0; kt < 4; ++kt)
        qf[kt] = *(const bf16x8*)(qfb + (size_t)gt * 2048 + kt * 512);

    f32x16 acc0 = {}, acc1 = {};

    if (c > 0) {
        const unsigned short* sb_ = states + (size_t)(bh * 32 + c - 1) * 4096 + l * 8;
        bf16x8 sf[4][2];
        #pragma unroll
        for (int kt = 0; kt < 4; ++kt)
            #pragma unroll
            for (int dh = 0; dh < 2; ++dh)
                sf[kt][dh] = *(const bf16x8*)(sb_ + kt * 1024 + dh * 512);
        f32x16 a0 = {}, a1 = {};
        #pragma unroll
        for (int kt = 0; kt < 4; ++kt) {
            a0 = mfma32(qf[kt], sf[kt][0], a0);
            a1 = mfma32(qf[kt], sf[kt][1], a1);
        }
        #pragma unroll
        for (int r = 0; r < 16; ++r) {
            const int crow = (r & 3) + (hi << 2) + ((r >> 2) << 3);
            const float sfac = 0.125f * exp2f(lg * (float)(32 * w + crow));
            acc0[r] = a0[r] * sfac;
            acc1[r] = a1[r] * sfac;
        }
    }

    float cf[16];
    #pragma unroll
    for (int r = 0; r < 16; ++r) {
        const int crow = (r & 3) + (hi << 2) + ((r >> 2) << 3);
        cf[r] = exp2f((float)(31 - crow) * lg);
    }
    for (int sl = 0; sl <= w; ++sl) {
        const int gs = 2 * c + sl;
        bf16x8 kc[4], vc[4];
        #pragma unroll
        for (int kt = 0; kt < 4; ++kt)
            kc[kt] = *(const bf16x8*)(kfb + (size_t)gs * 2048 + kt * 512);
        #pragma unroll
        for (int i = 0; i < 4; ++i)
            vc[i] = *(const bf16x8*)(vfb + (size_t)gs * 2048 + i * 512);

        f32x16 sc = {};
        #pragma unroll
        for (int kt = 0; kt < 4; ++kt) sc = mfma32(kc[kt], qf[kt], sc);

        const float rowf = 0.125f * exp2f((float)((w - sl) * 32 + l31 - 31) * lg);
        float wv_[16];
        if (sl == w) {
            #pragma unroll
            for (int r = 0; r < 16; ++r) {
                const int crow = (r & 3) + (hi << 2) + ((r >> 2) << 3);
                float t_ = sc[r] * rowf * cf[r];
                wv_[r] = (l31 >= crow) ? t_ : 0.0f;
            }
        } else {
            #pragma unroll
            for (int r = 0; r < 16; ++r) wv_[r] = sc[r] * rowf * cf[r];
        }
        unsigned pk_[8];
        #pragma unroll
        for (int i = 0; i < 8; ++i) pk_[i] = cvtpk(wv_[2 * i], wv_[2 * i + 1]);
        asm("v_permlane32_swap_b32 %0, %1" : "+v"(pk_[0]), "+v"(pk_[2]));
        asm("v_permlane32_swap_b32 %0, %1" : "+v"(pk_[1]), "+v"(pk_[3]));
        asm("v_permlane32_swap_b32 %0, %1" : "+v"(pk_[4]), "+v"(pk_[6]));
        asm("v_permlane32_swap_b32 %0, %1" : "+v"(pk_[5]), "+v"(pk_[7]));
        u32x4 f0v = { pk_[0], pk_[1], pk_[2], pk_[3] };
        u32x4 f1v = { pk_[4], pk_[5], pk_[6], pk_[7] };
        const bf16x8 pa0 = __builtin_bit_cast(bf16x8, f0v);
        const bf16x8 pa1 = __builtin_bit_cast(bf16x8, f1v);
        acc0 = mfma32(pa0, vc[0], acc0);
        acc0 = mfma32(pa1, vc[1], acc0);
        acc1 = mfma32(pa0, vc[2], acc1);
        acc1 = mfma32(pa1, vc[3], acc1);
    }

    #pragma unroll
    for (int r = 0; r < 16; ++r) {
        const int tl = (r & 3) + (hi << 2) + ((r >> 2) << 3);
        unsigned short* dst = ret + (size_t)(b * 2048 + gt * 32 + tl) * 1024 + h * 64 + l31;
        dst[0]  = f2bf(acc0[r]);
        dst[32] = f2bf(acc1[r]);
    }
}

// ---------------------------------------------------------------------------
// Kernel 3: out = ret @ wo.T, prefetch-overlap 2-phase (R21 version).
// ---------------------------------------------------------------------------
__global__ __launch_bounds__(256) void out_bf16(
    const unsigned short* __restrict__ ret, const unsigned short* __restrict__ wob,
    float* __restrict__ out)
{
    __shared__ unsigned short sR[128 * 64];
    __shared__ unsigned short sL[128 * 64];

    const int rblk = blockIdx.x;
    const int lblk = blockIdx.y;

    const int tid = threadIdx.x;
    const int l = tid & 63, w = tid >> 6;
    const int lrow = l & 15, koff4 = (l >> 4) * 4;
    const int swz = lrow & 7;
    const int wrow = (w >> 1) * 64, wcol = (w & 1) * 64;

    f32x4 acc[4][4] = {};

    const int srow = w * 32 + (l >> 3);
    const int scol = ((l & 7) ^ ((l >> 3) & 7)) * 8;
    const unsigned short* gR = ret + (size_t)(rblk * 128 + srow) * 1024 + scol;
    const unsigned short* gL = wob + (size_t)(lblk * 128 + srow) * 1024 + scol;
    unsigned short* lRb = sR + (w * 32) * 64;
    unsigned short* lLb = sL + (w * 32) * 64;

    auto stage = [&](int kk) {
        #pragma unroll
        for (int p = 0; p < 4; ++p) {
            gl16(gR + (size_t)p * 8 * 1024 + kk, lRb + p * 512);
            gl16(gL + (size_t)p * 8 * 1024 + kk, lLb + p * 512);
        }
    };

    stage(0);
    for (int kk = 0; kk < 1024; kk += 64) {
        asm volatile("s_waitcnt vmcnt(0)" ::: "memory");
        __builtin_amdgcn_s_barrier();
        __builtin_amdgcn_sched_barrier(0);

        bf16x8 aL[2][4], bR[2][4];
        #pragma unroll
        for (int kt = 0; kt < 2; ++kt)
            #pragma unroll
            for (int f = 0; f < 4; ++f) {
                const int co = ((kt * 4 + (l >> 4)) ^ swz) * 8;
                aL[kt][f] = *(const bf16x8*)&sL[(wcol + f * 16 + lrow) * 64 + co];
                bR[kt][f] = *(const bf16x8*)&sR[(wrow + f * 16 + lrow) * 64 + co];
            }
        asm volatile("s_waitcnt lgkmcnt(0)" ::: "memory");
        __builtin_amdgcn_sched_barrier(0);
        __builtin_amdgcn_s_barrier();
        __builtin_amdgcn_sched_barrier(0);

        if (kk + 64 < 1024) stage(kk + 64);

        __builtin_amdgcn_s_setprio(1);
        #pragma unroll
        for (int kt = 0; kt < 2; ++kt)
            #pragma unroll
            for (int af = 0; af < 4; ++af)
                #pragma unroll
                for (int bf = 0; bf < 4; ++bf)
                    acc[af][bf] = mfma16(aL[kt][af], bR[kt][bf], acc[af][bf]);
        __builtin_amdgcn_s_setprio(0);
    }

    #pragma unroll
    for (int af = 0; af < 4; ++af)
        #pragma unroll
        for (int bf = 0; bf < 4; ++bf) {
            const int m = rblk * 128 + wrow + bf * 16 + lrow;
            const int n0 = lblk * 128 + wcol + af * 16 + koff4;
            *(f32x4*)(out + (size_t)m * 1024 + n0) = acc[af][bf];
        }
}

extern "C" void kernel_launch(void* const* d_in, const int* in_sizes, int n_in,
                              void* d_out, int out_size, void* d_ws, size_t ws_size,
                              hipStream_t stream) {
    const float* x      = (const float*)d_in[0];
    const float* wq     = (const float*)d_in[1];
    const float* wk     = (const float*)d_in[2];
    const float* wv     = (const float*)d_in[3];
    const float* wo     = (const float*)d_in[4];
    const float* gammas = (const float*)d_in[5];
    float* out = (float*)d_out;

    unsigned short* ws = (unsigned short*)d_ws;
    const size_t M = 1024 * 1024;
    unsigned short* qf     = ws;
    unsigned short* kf     = ws + 4 * M;
    unsigned short* vf     = ws + 8 * M;
    unsigned short* ret    = ws + 12 * M;    // also xb (dead after qkv)
    unsigned short* xb     = ret;
    unsigned short* wqb    = ws + 16 * M;
    unsigned short* wkb    = ws + 17 * M;
    unsigned short* wvb    = ws + 18 * M;
    unsigned short* states = ws + 16 * M;    // aliases wq/wk/wv (dead after qkv)
    unsigned short* wob    = ws + 20 * M;    // OUTSIDE the states alias region

    convert_bf16<<<1024, 256, 0, stream>>>(x, wq, wk, wv, wo, xb, wqb, wkb, wvb, wob);
    qkv_bf16<<<dim3(32, 8, 3), 256, 0, stream>>>(xb, wqb, wkb, wvb, qf, kf, vf);
    a_state<<<1024, 128, 0, stream>>>(kf, vf, gammas, states);
    state_scan<<<128, 256, 0, stream>>>(states, gammas);
    chunk_out<<<1024, 128, 0, stream>>>(qf, kf, vf, states, gammas, ret);
    out_bf16<<<dim3(32, 8), 256, 0, stream>>>(ret, wob, out);
}